// Round 16
// baseline (198.554 us; speedup 1.0000x reference)
//
#include <hip/hip_runtime.h>
#include <cstdint>
#include <cstddef>

typedef __attribute__((ext_vector_type(8))) _Float16 f16x8;
typedef __attribute__((ext_vector_type(4))) _Float16 f16x4;
typedef __attribute__((ext_vector_type(4))) float f32x4;

#define MFMA_16x16x32(a, b, c) __builtin_amdgcn_mfma_f32_16x16x32_f16((a), (b), (c), 0, 0, 0)
#define MFMA_16x16x16(a, b, c) __builtin_amdgcn_mfma_f32_16x16x16f16((a), (b), (c), 0, 0, 0)

static constexpr int kB = 2, kS = 2048, kDim = 1024, kH = 16, kD = 64;
static constexpr int kM = kB * kS;  // 4096 rows total
// 1/sqrt(64) * log2(e), folded into Q at projection time
static constexpr float kQScale = 0.125f * 1.44269504088896340736f;
// -1e6 * log2(e): mask penalty in exp2 domain
static constexpr float kPenC = 1.44269504088896340736e6f;

// Raw workgroup barrier: drain only LDS ops (lgkmcnt), NOT vmcnt, so register
// prefetch loads stay in flight across the barrier.
__device__ __forceinline__ void wg_barrier_lds() {
  asm volatile("s_waitcnt lgkmcnt(0)" ::: "memory");
  __builtin_amdgcn_s_barrier();
}

// ---------------- elementwise f32 -> f16 ----------------
__global__ void cvt_f32_to_f16(const float* __restrict__ in, _Float16* __restrict__ out, int n8) {
  int i = blockIdx.x * blockDim.x + threadIdx.x;
  if (i >= n8) return;
  const float4* p = (const float4*)in + (size_t)i * 2;
  float4 a = p[0], b = p[1];
  f16x8 h;
  h[0] = (_Float16)a.x; h[1] = (_Float16)a.y; h[2] = (_Float16)a.z; h[3] = (_Float16)a.w;
  h[4] = (_Float16)b.x; h[5] = (_Float16)b.y; h[6] = (_Float16)b.z; h[7] = (_Float16)b.w;
  ((f16x8*)out)[i] = h;
}

// ------------- W [K][N] f32  ->  Wt [N][K] f16 (4 matrices) -------------
__global__ void transpose_cvt_w(const float* __restrict__ w0, const float* __restrict__ w1,
                                const float* __restrict__ w2, const float* __restrict__ w3,
                                _Float16* __restrict__ o0, _Float16* __restrict__ o1,
                                _Float16* __restrict__ o2, _Float16* __restrict__ o3) {
  const float* w; _Float16* o;
  switch (blockIdx.z) {
    case 0: w = w0; o = o0; break;
    case 1: w = w1; o = o1; break;
    case 2: w = w2; o = o2; break;
    default: w = w3; o = o3; break;
  }
  __shared__ alignas(16) _Float16 tile[64][72];
  const int kt = blockIdx.x * 64;
  const int nt = blockIdx.y * 64;
  const int tr = threadIdx.x >> 4;
  const int tc = threadIdx.x & 15;
#pragma unroll
  for (int rr = 0; rr < 4; ++rr) {
    int r = rr * 16 + tr;
    float4 v = *(const float4*)&w[(size_t)(kt + r) * kDim + nt + tc * 4];
    f16x4 hv;
    hv[0] = (_Float16)v.x; hv[1] = (_Float16)v.y; hv[2] = (_Float16)v.z; hv[3] = (_Float16)v.w;
    *(f16x4*)&tile[r][tc * 4] = hv;
  }
  __syncthreads();
#pragma unroll
  for (int rr = 0; rr < 4; ++rr) {
    int nl = rr * 16 + tr;
    f16x4 hv;
    hv[0] = tile[tc * 4 + 0][nl];
    hv[1] = tile[tc * 4 + 1][nl];
    hv[2] = tile[tc * 4 + 2][nl];
    hv[3] = tile[tc * 4 + 3][nl];
    *(f16x4*)&o[(size_t)(nt + nl) * kDim + kt + tc * 4] = hv;
  }
}

// ------------- QKV projection GEMM (measured-best: BK=64, reg-staged dbuf,
// lgkm-only barriers keep prefetch loads in flight across the barrier).
// Structure-space closed after 6 probes: this form won at 126-127.8us
// non-attn (R7/R12) vs 132.8 (m97 gload sbuf), 133.7 (sbuf reg), 135 (BK32),
// 139.9 (gload dbuf vmcnt0), 160.9 (A-direct).
__global__ __launch_bounds__(256, 2) void gemm_qkv(
    const _Float16* __restrict__ A,
    const _Float16* __restrict__ wt0, const _Float16* __restrict__ wt1, const _Float16* __restrict__ wt2,
    const float* __restrict__ bias0, const float* __restrict__ bias1, const float* __restrict__ bias2,
    _Float16* __restrict__ oq, _Float16* __restrict__ ok, _Float16* __restrict__ ov) {
  const _Float16* Bt; const float* bias; _Float16* out;
  switch (blockIdx.z) {
    case 0: Bt = wt0; bias = bias0; out = oq; break;
    case 1: Bt = wt1; bias = bias1; out = ok; break;
    default: Bt = wt2; bias = bias2; out = ov; break;
  }
  __shared__ alignas(16) _Float16 As[2][128 * 72];
  __shared__ alignas(16) _Float16 Bs[2][128 * 72];
  const int tid = threadIdx.x;
  const int lane = tid & 63;
  const int wave = tid >> 6;
  const int wm = wave & 1, wn = wave >> 1;
  const int l15 = lane & 15, quad = lane >> 4;
  const int m0 = blockIdx.x * 128, n0 = blockIdx.y * 128;

  const int srow = tid >> 3;             // staging row (tid + 256*i -> row = srow + 32*i)
  const int skc = (tid & 7) * 8;         // staging k-offset

  f32x4 acc[4][4] = {};
  f16x8 ra[4], rb[4];

#pragma unroll
  for (int i = 0; i < 4; ++i) {
    int row = srow + 32 * i;
    ra[i] = *(const f16x8*)&A[(size_t)(m0 + row) * kDim + skc];
    rb[i] = *(const f16x8*)&Bt[(size_t)(n0 + row) * kDim + skc];
  }
#pragma unroll
  for (int i = 0; i < 4; ++i) {
    int row = srow + 32 * i;
    *(f16x8*)&As[0][row * 72 + skc] = ra[i];
    *(f16x8*)&Bs[0][row * 72 + skc] = rb[i];
  }

  for (int kt = 0; kt < 16; ++kt) {
    const int cur = kt & 1;
    if (kt + 1 < 16) {
      int k0 = (kt + 1) * 64;
#pragma unroll
      for (int i = 0; i < 4; ++i) {
        int row = srow + 32 * i;
        ra[i] = *(const f16x8*)&A[(size_t)(m0 + row) * kDim + k0 + skc];
        rb[i] = *(const f16x8*)&Bt[(size_t)(n0 + row) * kDim + k0 + skc];
      }
    }
    wg_barrier_lds();  // writes to buffer `cur` (prev iter / prologue) complete
#pragma unroll
    for (int kk = 0; kk < 2; ++kk) {
      f16x8 af[4], bf[4];
#pragma unroll
      for (int t = 0; t < 4; ++t) af[t] = *(const f16x8*)&As[cur][(wm * 64 + t * 16 + l15) * 72 + kk * 32 + quad * 8];
#pragma unroll
      for (int t = 0; t < 4; ++t) bf[t] = *(const f16x8*)&Bs[cur][(wn * 64 + t * 16 + l15) * 72 + kk * 32 + quad * 8];
      __builtin_amdgcn_s_setprio(1);
#pragma unroll
      for (int i = 0; i < 4; ++i)
#pragma unroll
        for (int j = 0; j < 4; ++j)
          acc[i][j] = MFMA_16x16x32(af[i], bf[j], acc[i][j]);
      __builtin_amdgcn_s_setprio(0);
    }
    if (kt + 1 < 16) {
#pragma unroll
      for (int i = 0; i < 4; ++i) {
        int row = srow + 32 * i;
        *(f16x8*)&As[cur ^ 1][row * 72 + skc] = ra[i];
        *(f16x8*)&Bs[cur ^ 1][row * 72 + skc] = rb[i];
      }
    }
  }

  const int mbase = m0 + wm * 64 + quad * 4;
  const int nbase = n0 + wn * 64 + l15;
  if (blockIdx.z == 2) {
#pragma unroll
    for (int j = 0; j < 4; ++j) {
      int n = nbase + j * 16;
      float bv = bias[n];
      int h = n >> 6, d = n & 63;
#pragma unroll
      for (int i = 0; i < 4; ++i) {
        int m = mbase + i * 16;
        int b = m >> 11, s = m & (kS - 1);
        f16x4 hv;
#pragma unroll
        for (int r = 0; r < 4; ++r) hv[r] = (_Float16)(acc[i][j][r] + bv);
        *(f16x4*)&out[((size_t)((b * kH + h) * kD + d)) * kS + s] = hv;
      }
    }
  } else {
    const float osc = (blockIdx.z == 0) ? kQScale : 1.0f;
#pragma unroll
    for (int j = 0; j < 4; ++j) {
      int n = nbase + j * 16;
      float bv = bias[n];
      int h = n >> 6, d = n & 63;
#pragma unroll
      for (int i = 0; i < 4; ++i) {
        int mrow = mbase + i * 16;
#pragma unroll
        for (int r = 0; r < 4; ++r) {
          int m = mrow + r;
          int b = m >> 11, s = m & (kS - 1);
          out[(size_t)(((b * kH + h) * kS) + s) * kD + d] = (_Float16)((acc[i][j][r] + bv) * osc);
        }
      }
    }
  }
}

// ------------- flash attention, S^T formulation, v7 (63.9-66.6us, 5x reproduced) -----
__global__ __launch_bounds__(256, 2) void attn(
    const _Float16* __restrict__ Q, const _Float16* __restrict__ K,
    const _Float16* __restrict__ V, const float* __restrict__ mask,
    _Float16* __restrict__ ctx) {
  const int id = blockIdx.x;
  const int logical = (id & 7) * 64 + (id >> 3);
  const int bh = logical >> 4;    // 0..31
  const int qblk = logical & 15;  // 0..15
  const int b = bh >> 4;
  const int q0 = qblk * 128;
  const int tid = threadIdx.x, lane = tid & 63, wave = tid >> 6;
  const int l15 = lane & 15, quad = lane >> 4;

  __shared__ alignas(16) _Float16 Ks[2][128 * 72];  // [key][d], stride 144B
  __shared__ alignas(16) _Float16 Vs[2][64 * 136];  // [d][key], stride 272B
  __shared__ alignas(16) float pens[kS];            // (mask-1)*kPenC for all keys

  const _Float16* Qh = Q + (size_t)bh * kS * kD;
  const _Float16* Kh = K + (size_t)bh * kS * kD;
  const _Float16* Vh = V + (size_t)bh * kS * kD;  // [d][s]

#pragma unroll
  for (int i = 0; i < 2; ++i) {
    float4 mv4 = *(const float4*)&mask[(size_t)b * kS + tid * 8 + i * 4];
    float4 pv;
    pv.x = (mv4.x - 1.0f) * kPenC;
    pv.y = (mv4.y - 1.0f) * kPenC;
    pv.z = (mv4.z - 1.0f) * kPenC;
    pv.w = (mv4.w - 1.0f) * kPenC;
    *(float4*)&pens[tid * 8 + i * 4] = pv;
  }

  f16x8 qf[2][2];
#pragma unroll
  for (int t = 0; t < 2; ++t) {
    int qrow = q0 + wave * 32 + t * 16 + l15;
#pragma unroll
    for (int kk = 0; kk < 2; ++kk)
      qf[t][kk] = *(const f16x8*)&Qh[(size_t)qrow * kD + kk * 32 + quad * 8];
  }

  f16x4 ones4;
#pragma unroll
  for (int i = 0; i < 4; ++i) ones4[i] = (_Float16)1.0f;

  f32x4 o_acc[2][4] = {};  // O[q][d]: lane holds q=quad*4+r, d=c*16+l15
  f32x4 l_acc[2] = {};     // l[q=quad*4+r]

  const int srow = tid >> 3;        // K staging row base (0..31)
  const int skc = (tid & 7) * 8;    // K staging d-offset
  const int vrow = tid >> 4;        // V staging row base (0..15)
  const int vcol = (tid & 15) * 8;  // V staging key-offset

  f16x8 kreg[4], vreg[4];
#pragma unroll
  for (int i = 0; i < 4; ++i)
    kreg[i] = *(const f16x8*)&Kh[(size_t)(srow + 32 * i) * kD + skc];
#pragma unroll
  for (int i = 0; i < 4; ++i)
    vreg[i] = *(const f16x8*)&Vh[(size_t)(vrow + 16 * i) * kS + vcol];
#pragma unroll
  for (int i = 0; i < 4; ++i)
    *(f16x8*)&Ks[0][(srow + 32 * i) * 72 + skc] = kreg[i];
#pragma unroll
  for (int i = 0; i < 4; ++i)
    *(f16x8*)&Vs[0][(vrow + 16 * i) * 136 + vcol] = vreg[i];

  for (int it = 0; it < 16; ++it) {
    const int cur = it & 1;
    const int kb = it * 128;
    if (it + 1 < 16) {  // issue next K/V tiles; fly under compute (no vmcnt drain)
#pragma unroll
      for (int i = 0; i < 4; ++i)
        kreg[i] = *(const f16x8*)&Kh[(size_t)(kb + 128 + srow + 32 * i) * kD + skc];
#pragma unroll
      for (int i = 0; i < 4; ++i)
        vreg[i] = *(const f16x8*)&Vh[(size_t)(vrow + 16 * i) * kS + kb + 128 + vcol];
    }
    wg_barrier_lds();  // buf[cur] staged (prev iter / prologue); prev reads of buf[cur] done

#pragma unroll
    for (int colt = 0; colt < 8; ++colt) {
      f32x4 pn = *(const f32x4*)&pens[kb + colt * 16 + quad * 4];
      f16x8 kf0 = *(const f16x8*)&Ks[cur][(colt * 16 + l15) * 72 + quad * 8];
      f16x8 kf1 = *(const f16x8*)&Ks[cur][(colt * 16 + l15) * 72 + 32 + quad * 8];
      f32x4 s0 = pn, s1 = pn;
      s0 = MFMA_16x16x32(kf0, qf[0][0], s0);
      s0 = MFMA_16x16x32(kf1, qf[0][1], s0);
      s1 = MFMA_16x16x32(kf0, qf[1][0], s1);
      s1 = MFMA_16x16x32(kf1, qf[1][1], s1);
      f16x4 vf0 = *(const f16x4*)&Vs[cur][(0 * 16 + l15) * 136 + colt * 16 + quad * 4];
      f16x4 vf1 = *(const f16x4*)&Vs[cur][(1 * 16 + l15) * 136 + colt * 16 + quad * 4];
      f16x4 vf2 = *(const f16x4*)&Vs[cur][(2 * 16 + l15) * 136 + colt * 16 + quad * 4];
      f16x4 vf3 = *(const f16x4*)&Vs[cur][(3 * 16 + l15) * 136 + colt * 16 + quad * 4];
      f16x4 pa0, pa1;
#pragma unroll
      for (int r = 0; r < 4; ++r) {
        pa0[r] = (_Float16)__builtin_exp2f(s0[r]);
        pa1[r] = (_Float16)__builtin_exp2f(s1[r]);
      }
      __builtin_amdgcn_s_setprio(1);
      o_acc[0][0] = MFMA_16x16x16(pa0, vf0, o_acc[0][0]);
      o_acc[0][1] = MFMA_16x16x16(pa0, vf1, o_acc[0][1]);
      o_acc[0][2] = MFMA_16x16x16(pa0, vf2, o_acc[0][2]);
      o_acc[0][3] = MFMA_16x16x16(pa0, vf3, o_acc[0][3]);
      o_acc[1][0] = MFMA_16x16x16(pa1, vf0, o_acc[1][0]);
      o_acc[1][1] = MFMA_16x16x16(pa1, vf1, o_acc[1][1]);
      o_acc[1][2] = MFMA_16x16x16(pa1, vf2, o_acc[1][2]);
      o_acc[1][3] = MFMA_16x16x16(pa1, vf3, o_acc[1][3]);
      l_acc[0] = MFMA_16x16x16(pa0, ones4, l_acc[0]);
      l_acc[1] = MFMA_16x16x16(pa1, ones4, l_acc[1]);
      __builtin_amdgcn_s_setprio(0);
    }

    if (it + 1 < 16) {
#pragma unroll
      for (int i = 0; i < 4; ++i)
        *(f16x8*)&Ks[cur ^ 1][(srow + 32 * i) * 72 + skc] = kreg[i];
#pragma unroll
      for (int i = 0; i < 4; ++i)
        *(f16x8*)&Vs[cur ^ 1][(vrow + 16 * i) * 136 + vcol] = vreg[i];
    }
  }

  const int h = bh & 15;
#pragma unroll
  for (int t = 0; t < 2; ++t) {
    f32x4 linv;
#pragma unroll
    for (int r = 0; r < 4; ++r) linv[r] = 1.0f / l_acc[t][r];
    int qbase = q0 + wave * 32 + t * 16 + quad * 4;
#pragma unroll
    for (int c = 0; c < 4; ++c) {
#pragma unroll
      for (int r = 0; r < 4; ++r) {
        ctx[((size_t)(b * kS + qbase + r)) * kDim + h * kD + c * 16 + l15] =
            (_Float16)(o_acc[t][c][r] * linv[r]);
      }
    }
  }
}

// ------------- output GEMM (measured-best: BM=64, BK=64 reg-staged dbuf, lgkm barriers) -------------
__global__ __launch_bounds__(256, 2) void gemm_out(
    const _Float16* __restrict__ A, const _Float16* __restrict__ Bt,
    const float* __restrict__ bias, float* __restrict__ out) {
  __shared__ alignas(16) _Float16 As[2][64 * 72];
  __shared__ alignas(16) _Float16 Bs[2][128 * 72];
  const int tid = threadIdx.x;
  const int lane = tid & 63;
  const int wave = tid >> 6;
  const int wm = wave & 1, wn = wave >> 1;   // 2x2 waves: 32M x 64N each
  const int l15 = lane & 15, quad = lane >> 4;
  const int m0 = blockIdx.x * 64, n0 = blockIdx.y * 128;

  const int srow = tid >> 3;
  const int skc = (tid & 7) * 8;

  f32x4 acc[2][4] = {};
  f16x8 ra[2], rb[4];

#pragma unroll
  for (int i = 0; i < 2; ++i)
    ra[i] = *(const f16x8*)&A[(size_t)(m0 + srow + 32 * i) * kDim + skc];
#pragma unroll
  for (int i = 0; i < 4; ++i)
    rb[i] = *(const f16x8*)&Bt[(size_t)(n0 + srow + 32 * i) * kDim + skc];
#pragma unroll
  for (int i = 0; i < 2; ++i)
    *(f16x8*)&As[0][(srow + 32 * i) * 72 + skc] = ra[i];
#pragma unroll
  for (int i = 0; i < 4; ++i)
    *(f16x8*)&Bs[0][(srow + 32 * i) * 72 + skc] = rb[i];

  for (int kt = 0; kt < 16; ++kt) {
    const int cur = kt & 1;
    if (kt + 1 < 16) {
      int k0 = (kt + 1) * 64;
#pragma unroll
      for (int i = 0; i < 2; ++i)
        ra[i] = *(const f16x8*)&A[(size_t)(m0 + srow + 32 * i) * kDim + k0 + skc];
#pragma unroll
      for (int i = 0; i < 4; ++i)
        rb[i] = *(const f16x8*)&Bt[(size_t)(n0 + srow + 32 * i) * kDim + k0 + skc];
    }
    wg_barrier_lds();
#pragma unroll
    for (int kk = 0; kk < 2; ++kk) {
      f16x8 af[2], bf[4];
#pragma unroll
      for (int t = 0; t < 2; ++t) af[t] = *(const f16x8*)&As[cur][(wm * 32 + t * 16 + l15) * 72 + kk * 32 + quad * 8];
#pragma unroll
      for (int t = 0; t < 4; ++t) bf[t] = *(const f16x8*)&Bs[cur][(wn * 64 + t * 16 + l15) * 72 + kk * 32 + quad * 8];
      __builtin_amdgcn_s_setprio(1);
#pragma unroll
      for (int i = 0; i < 2; ++i)
#pragma unroll
        for (int j = 0; j < 4; ++j)
          acc[i][j] = MFMA_16x16x32(af[i], bf[j], acc[i][j]);
      __builtin_amdgcn_s_setprio(0);
    }
    if (kt + 1 < 16) {
#pragma unroll
      for (int i = 0; i < 2; ++i)
        *(f16x8*)&As[cur ^ 1][(srow + 32 * i) * 72 + skc] = ra[i];
#pragma unroll
      for (int i = 0; i < 4; ++i)
        *(f16x8*)&Bs[cur ^ 1][(srow + 32 * i) * 72 + skc] = rb[i];
    }
  }

  const int mbase = m0 + wm * 32 + quad * 4;
  const int nbase = n0 + wn * 64 + l15;
#pragma unroll
  for (int j = 0; j < 4; ++j) {
    int n = nbase + j * 16;
    float bv = bias[n];
#pragma unroll
    for (int i = 0; i < 2; ++i) {
      int mrow = mbase + i * 16;
#pragma unroll
      for (int r = 0; r < 4; ++r)
        out[(size_t)(mrow + r) * kDim + n] = acc[i][j][r] + bv;
    }
  }
}

extern "C" void kernel_launch(void* const* d_in, const int* in_sizes, int n_in,
                              void* d_out, int out_size, void* d_ws, size_t ws_size,
                              hipStream_t stream) {
  (void)in_sizes; (void)n_in; (void)out_size; (void)ws_size;
  const float* X    = (const float*)d_in[0];
  const float* mask = (const float*)d_in[1];
  const float* Wq   = (const float*)d_in[2];
  const float* bq   = (const float*)d_in[3];
  const float* Wk   = (const float*)d_in[4];
  const float* bk   = (const float*)d_in[5];
  const float* Wv   = (const float*)d_in[6];
  const float* bv   = (const float*)d_in[7];
  const float* Wo   = (const float*)d_in[8];
  const float* bo   = (const float*)d_in[9];
  float* out = (float*)d_out;

  char* ws = (char*)d_ws;
  _Float16* Xh   = (_Float16*)(ws);                        // 8 MB
  _Float16* Wqt  = (_Float16*)(ws + ((size_t)8  << 20));   // 2 MB each
  _Float16* Wkt  = (_Float16*)(ws + ((size_t)10 << 20));
  _Float16* Wvt  = (_Float16*)(ws + ((size_t)12 << 20));
  _Float16* Wot  = (_Float16*)(ws + ((size_t)14 << 20));
  _Float16* Qh   = (_Float16*)(ws + ((size_t)16 << 20));   // 8 MB each
  _Float16* Kh   = (_Float16*)(ws + ((size_t)24 << 20));
  _Float16* Vh   = (_Float16*)(ws + ((size_t)32 << 20));   // [B][H][D][S]
  _Float16* Ch   = (_Float16*)(ws + ((size_t)40 << 20));   // 8 MB

  cvt_f32_to_f16<<<dim3(kM * kDim / 8 / 256), dim3(256), 0, stream>>>(X, Xh, kM * kDim / 8);
  transpose_cvt_w<<<dim3(16, 16, 4), dim3(256), 0, stream>>>(Wq, Wk, Wv, Wo, Wqt, Wkt, Wvt, Wot);
  gemm_qkv<<<dim3(32, 8, 3), dim3(256), 0, stream>>>(Xh, Wqt, Wkt, Wvt, bq, bk, bv, Qh, Kh, Vh);
  attn<<<dim3(512), dim3(256), 0, stream>>>(Qh, Kh, Vh, mask, Ch);
  gemm_out<<<dim3(64, 8), dim3(256), 0, stream>>>(Ch, Wot, bo, out);
}

// Round 17
// 195.645 us; speedup vs baseline: 1.0149x; 1.0149x over previous
//
#include <hip/hip_runtime.h>
#include <cstdint>
#include <cstddef>

typedef __attribute__((ext_vector_type(8))) _Float16 f16x8;
typedef __attribute__((ext_vector_type(4))) _Float16 f16x4;
typedef __attribute__((ext_vector_type(4))) float f32x4;

#define MFMA_16x16x32(a, b, c) __builtin_amdgcn_mfma_f32_16x16x32_f16((a), (b), (c), 0, 0, 0)

static constexpr int kB = 2, kS = 2048, kDim = 1024, kH = 16, kD = 64;
static constexpr int kM = kB * kS;  // 4096 rows total
// 1/sqrt(64) * log2(e), folded into Q at projection time
static constexpr float kQScale = 0.125f * 1.44269504088896340736f;
// -1e6 * log2(e): mask penalty in exp2 domain
static constexpr float kPenC = 1.44269504088896340736e6f;

// Raw workgroup barrier: drain only LDS ops (lgkmcnt), NOT vmcnt, so register
// prefetch loads stay in flight across the barrier.
__device__ __forceinline__ void wg_barrier_lds() {
  asm volatile("s_waitcnt lgkmcnt(0)" ::: "memory");
  __builtin_amdgcn_s_barrier();
}

// ---------------- elementwise f32 -> f16 ----------------
__global__ void cvt_f32_to_f16(const float* __restrict__ in, _Float16* __restrict__ out, int n8) {
  int i = blockIdx.x * blockDim.x + threadIdx.x;
  if (i >= n8) return;
  const float4* p = (const float4*)in + (size_t)i * 2;
  float4 a = p[0], b = p[1];
  f16x8 h;
  h[0] = (_Float16)a.x; h[1] = (_Float16)a.y; h[2] = (_Float16)a.z; h[3] = (_Float16)a.w;
  h[4] = (_Float16)b.x; h[5] = (_Float16)b.y; h[6] = (_Float16)b.z; h[7] = (_Float16)b.w;
  ((f16x8*)out)[i] = h;
}

// ------------- W [K][N] f32  ->  Wt [N][K] f16 (4 matrices) -------------
__global__ void transpose_cvt_w(const float* __restrict__ w0, const float* __restrict__ w1,
                                const float* __restrict__ w2, const float* __restrict__ w3,
                                _Float16* __restrict__ o0, _Float16* __restrict__ o1,
                                _Float16* __restrict__ o2, _Float16* __restrict__ o3) {
  const float* w; _Float16* o;
  switch (blockIdx.z) {
    case 0: w = w0; o = o0; break;
    case 1: w = w1; o = o1; break;
    case 2: w = w2; o = o2; break;
    default: w = w3; o = o3; break;
  }
  __shared__ alignas(16) _Float16 tile[64][72];
  const int kt = blockIdx.x * 64;
  const int nt = blockIdx.y * 64;
  const int tr = threadIdx.x >> 4;
  const int tc = threadIdx.x & 15;
#pragma unroll
  for (int rr = 0; rr < 4; ++rr) {
    int r = rr * 16 + tr;
    float4 v = *(const float4*)&w[(size_t)(kt + r) * kDim + nt + tc * 4];
    f16x4 hv;
    hv[0] = (_Float16)v.x; hv[1] = (_Float16)v.y; hv[2] = (_Float16)v.z; hv[3] = (_Float16)v.w;
    *(f16x4*)&tile[r][tc * 4] = hv;
  }
  __syncthreads();
#pragma unroll
  for (int rr = 0; rr < 4; ++rr) {
    int nl = rr * 16 + tr;
    f16x4 hv;
    hv[0] = tile[tc * 4 + 0][nl];
    hv[1] = tile[tc * 4 + 1][nl];
    hv[2] = tile[tc * 4 + 2][nl];
    hv[3] = tile[tc * 4 + 3][nl];
    *(f16x4*)&o[(size_t)(nt + nl) * kDim + kt + tc * 4] = hv;
  }
}

// ------------- QKV projection GEMM (measured-best: BK=64, reg-staged dbuf,
// lgkm-only barriers). Structure-space closed after 6 probes.
__global__ __launch_bounds__(256, 2) void gemm_qkv(
    const _Float16* __restrict__ A,
    const _Float16* __restrict__ wt0, const _Float16* __restrict__ wt1, const _Float16* __restrict__ wt2,
    const float* __restrict__ bias0, const float* __restrict__ bias1, const float* __restrict__ bias2,
    _Float16* __restrict__ oq, _Float16* __restrict__ ok, _Float16* __restrict__ ov) {
  const _Float16* Bt; const float* bias; _Float16* out;
  switch (blockIdx.z) {
    case 0: Bt = wt0; bias = bias0; out = oq; break;
    case 1: Bt = wt1; bias = bias1; out = ok; break;
    default: Bt = wt2; bias = bias2; out = ov; break;
  }
  __shared__ alignas(16) _Float16 As[2][128 * 72];
  __shared__ alignas(16) _Float16 Bs[2][128 * 72];
  const int tid = threadIdx.x;
  const int lane = tid & 63;
  const int wave = tid >> 6;
  const int wm = wave & 1, wn = wave >> 1;
  const int l15 = lane & 15, quad = lane >> 4;
  const int m0 = blockIdx.x * 128, n0 = blockIdx.y * 128;

  const int srow = tid >> 3;             // staging row (tid + 256*i -> row = srow + 32*i)
  const int skc = (tid & 7) * 8;         // staging k-offset

  f32x4 acc[4][4] = {};
  f16x8 ra[4], rb[4];

#pragma unroll
  for (int i = 0; i < 4; ++i) {
    int row = srow + 32 * i;
    ra[i] = *(const f16x8*)&A[(size_t)(m0 + row) * kDim + skc];
    rb[i] = *(const f16x8*)&Bt[(size_t)(n0 + row) * kDim + skc];
  }
#pragma unroll
  for (int i = 0; i < 4; ++i) {
    int row = srow + 32 * i;
    *(f16x8*)&As[0][row * 72 + skc] = ra[i];
    *(f16x8*)&Bs[0][row * 72 + skc] = rb[i];
  }

  for (int kt = 0; kt < 16; ++kt) {
    const int cur = kt & 1;
    if (kt + 1 < 16) {
      int k0 = (kt + 1) * 64;
#pragma unroll
      for (int i = 0; i < 4; ++i) {
        int row = srow + 32 * i;
        ra[i] = *(const f16x8*)&A[(size_t)(m0 + row) * kDim + k0 + skc];
        rb[i] = *(const f16x8*)&Bt[(size_t)(n0 + row) * kDim + k0 + skc];
      }
    }
    wg_barrier_lds();  // writes to buffer `cur` (prev iter / prologue) complete
#pragma unroll
    for (int kk = 0; kk < 2; ++kk) {
      f16x8 af[4], bf[4];
#pragma unroll
      for (int t = 0; t < 4; ++t) af[t] = *(const f16x8*)&As[cur][(wm * 64 + t * 16 + l15) * 72 + kk * 32 + quad * 8];
#pragma unroll
      for (int t = 0; t < 4; ++t) bf[t] = *(const f16x8*)&Bs[cur][(wn * 64 + t * 16 + l15) * 72 + kk * 32 + quad * 8];
      __builtin_amdgcn_s_setprio(1);
#pragma unroll
      for (int i = 0; i < 4; ++i)
#pragma unroll
        for (int j = 0; j < 4; ++j)
          acc[i][j] = MFMA_16x16x32(af[i], bf[j], acc[i][j]);
      __builtin_amdgcn_s_setprio(0);
    }
    if (kt + 1 < 16) {
#pragma unroll
      for (int i = 0; i < 4; ++i) {
        int row = srow + 32 * i;
        *(f16x8*)&As[cur ^ 1][row * 72 + skc] = ra[i];
        *(f16x8*)&Bs[cur ^ 1][row * 72 + skc] = rb[i];
      }
    }
  }

  const int mbase = m0 + wm * 64 + quad * 4;
  const int nbase = n0 + wn * 64 + l15;
  if (blockIdx.z == 2) {
#pragma unroll
    for (int j = 0; j < 4; ++j) {
      int n = nbase + j * 16;
      float bv = bias[n];
      int h = n >> 6, d = n & 63;
#pragma unroll
      for (int i = 0; i < 4; ++i) {
        int m = mbase + i * 16;
        int b = m >> 11, s = m & (kS - 1);
        f16x4 hv;
#pragma unroll
        for (int r = 0; r < 4; ++r) hv[r] = (_Float16)(acc[i][j][r] + bv);
        *(f16x4*)&out[((size_t)((b * kH + h) * kD + d)) * kS + s] = hv;
      }
    }
  } else {
    const float osc = (blockIdx.z == 0) ? kQScale : 1.0f;
#pragma unroll
    for (int j = 0; j < 4; ++j) {
      int n = nbase + j * 16;
      float bv = bias[n];
      int h = n >> 6, d = n & 63;
#pragma unroll
      for (int i = 0; i < 4; ++i) {
        int mrow = mbase + i * 16;
#pragma unroll
        for (int r = 0; r < 4; ++r) {
          int m = mrow + r;
          int b = m >> 11, s = m & (kS - 1);
          out[(size_t)(((b * kH + h) * kS) + s) * kD + d] = (_Float16)((acc[i][j][r] + bv) * osc);
        }
      }
    }
  }
}

// ------------- flash attention v9: K=32 PV via k-slot permutation -------------
// v7 issued 96 K=16 PV/l MFMAs per iter (each colt's P fills only 4 k-slots).
// v9 pairs colts (c0,c1): lane's 8 P-values form a full 16x16x32 A-fragment
// under the k-slot bijection  slot quad*8+j  <->  key c0*16+quad*4+j (j<4),
//                                                c1*16+quad*4+(j-4) (j>=4).
// MFMA's k-sum is permutation-invariant, so PV is exact as long as V's
// B-fragment applies the SAME permutation -- which is just the two f16x4
// Vs reads we already did, packed into one f16x8. PV+l MFMA count per iter:
// 96 -> 48 (K=32). LDS reads, exp2, staging, barriers unchanged.
// A/B k-layout (k = quad*8+j) is confirmed by the GEMM fragment addressing
// used in every passing round. C/D layout identical for both shapes.
__global__ __launch_bounds__(256, 2) void attn(
    const _Float16* __restrict__ Q, const _Float16* __restrict__ K,
    const _Float16* __restrict__ V, const float* __restrict__ mask,
    _Float16* __restrict__ ctx) {
  const int id = blockIdx.x;
  const int logical = (id & 7) * 64 + (id >> 3);
  const int bh = logical >> 4;    // 0..31
  const int qblk = logical & 15;  // 0..15
  const int b = bh >> 4;
  const int q0 = qblk * 128;
  const int tid = threadIdx.x, lane = tid & 63, wave = tid >> 6;
  const int l15 = lane & 15, quad = lane >> 4;

  __shared__ alignas(16) _Float16 Ks[2][128 * 72];  // [key][d], stride 144B
  __shared__ alignas(16) _Float16 Vs[2][64 * 136];  // [d][key], stride 272B
  __shared__ alignas(16) float pens[kS];            // (mask-1)*kPenC for all keys

  const _Float16* Qh = Q + (size_t)bh * kS * kD;
  const _Float16* Kh = K + (size_t)bh * kS * kD;
  const _Float16* Vh = V + (size_t)bh * kS * kD;  // [d][s]

#pragma unroll
  for (int i = 0; i < 2; ++i) {
    float4 mv4 = *(const float4*)&mask[(size_t)b * kS + tid * 8 + i * 4];
    float4 pv;
    pv.x = (mv4.x - 1.0f) * kPenC;
    pv.y = (mv4.y - 1.0f) * kPenC;
    pv.z = (mv4.z - 1.0f) * kPenC;
    pv.w = (mv4.w - 1.0f) * kPenC;
    *(float4*)&pens[tid * 8 + i * 4] = pv;
  }

  f16x8 qf[2][2];
#pragma unroll
  for (int t = 0; t < 2; ++t) {
    int qrow = q0 + wave * 32 + t * 16 + l15;
#pragma unroll
    for (int kk = 0; kk < 2; ++kk)
      qf[t][kk] = *(const f16x8*)&Qh[(size_t)qrow * kD + kk * 32 + quad * 8];
  }

  f16x8 ones8;
#pragma unroll
  for (int i = 0; i < 8; ++i) ones8[i] = (_Float16)1.0f;

  f32x4 o_acc[2][4] = {};  // O[q][d]: lane holds q=quad*4+r, d=c*16+l15
  f32x4 l_acc[2] = {};     // l[q=quad*4+r]

  const int srow = tid >> 3;        // K staging row base (0..31)
  const int skc = (tid & 7) * 8;    // K staging d-offset
  const int vrow = tid >> 4;        // V staging row base (0..15)
  const int vcol = (tid & 15) * 8;  // V staging key-offset

  f16x8 kreg[4], vreg[4];
#pragma unroll
  for (int i = 0; i < 4; ++i)
    kreg[i] = *(const f16x8*)&Kh[(size_t)(srow + 32 * i) * kD + skc];
#pragma unroll
  for (int i = 0; i < 4; ++i)
    vreg[i] = *(const f16x8*)&Vh[(size_t)(vrow + 16 * i) * kS + vcol];
#pragma unroll
  for (int i = 0; i < 4; ++i)
    *(f16x8*)&Ks[0][(srow + 32 * i) * 72 + skc] = kreg[i];
#pragma unroll
  for (int i = 0; i < 4; ++i)
    *(f16x8*)&Vs[0][(vrow + 16 * i) * 136 + vcol] = vreg[i];

  for (int it = 0; it < 16; ++it) {
    const int cur = it & 1;
    const int kb = it * 128;
    if (it + 1 < 16) {  // issue next K/V tiles; fly under compute (no vmcnt drain)
#pragma unroll
      for (int i = 0; i < 4; ++i)
        kreg[i] = *(const f16x8*)&Kh[(size_t)(kb + 128 + srow + 32 * i) * kD + skc];
#pragma unroll
      for (int i = 0; i < 4; ++i)
        vreg[i] = *(const f16x8*)&Vh[(size_t)(vrow + 16 * i) * kS + kb + 128 + vcol];
    }
    wg_barrier_lds();  // buf[cur] staged (prev iter / prologue); prev reads of buf[cur] done

#pragma unroll
    for (int p = 0; p < 4; ++p) {
      const int c0 = p * 2, c1 = p * 2 + 1;
      // S^T for both colts of the pair (4 K=32 MFMAs each, same as v7)
      f32x4 pnA = *(const f32x4*)&pens[kb + c0 * 16 + quad * 4];
      f32x4 pnB = *(const f32x4*)&pens[kb + c1 * 16 + quad * 4];
      f16x8 kf0a = *(const f16x8*)&Ks[cur][(c0 * 16 + l15) * 72 + quad * 8];
      f16x8 kf1a = *(const f16x8*)&Ks[cur][(c0 * 16 + l15) * 72 + 32 + quad * 8];
      f16x8 kf0b = *(const f16x8*)&Ks[cur][(c1 * 16 + l15) * 72 + quad * 8];
      f16x8 kf1b = *(const f16x8*)&Ks[cur][(c1 * 16 + l15) * 72 + 32 + quad * 8];
      f32x4 s0a = pnA, s1a = pnA, s0b = pnB, s1b = pnB;
      s0a = MFMA_16x16x32(kf0a, qf[0][0], s0a);
      s0a = MFMA_16x16x32(kf1a, qf[0][1], s0a);
      s1a = MFMA_16x16x32(kf0a, qf[1][0], s1a);
      s1a = MFMA_16x16x32(kf1a, qf[1][1], s1a);
      s0b = MFMA_16x16x32(kf0b, qf[0][0], s0b);
      s0b = MFMA_16x16x32(kf1b, qf[0][1], s0b);
      s1b = MFMA_16x16x32(kf0b, qf[1][0], s1b);
      s1b = MFMA_16x16x32(kf1b, qf[1][1], s1b);
      // V B-fragments: slot j<4 = key c0*16+quad*4+j, j>=4 = key c1*16+quad*4+(j-4)
      f16x8 vfp[4];
#pragma unroll
      for (int ct = 0; ct < 4; ++ct) {
        f16x4 lo = *(const f16x4*)&Vs[cur][(ct * 16 + l15) * 136 + c0 * 16 + quad * 4];
        f16x4 hi = *(const f16x4*)&Vs[cur][(ct * 16 + l15) * 136 + c1 * 16 + quad * 4];
        *(f16x4*)&vfp[ct] = lo;
        *((f16x4*)&vfp[ct] + 1) = hi;
      }
      // P = exp2(S^T): pack both colts into the 8-slot A-fragment
      f16x8 pa0, pa1;
#pragma unroll
      for (int r = 0; r < 4; ++r) {
        pa0[r]     = (_Float16)__builtin_exp2f(s0a[r]);
        pa0[4 + r] = (_Float16)__builtin_exp2f(s0b[r]);
        pa1[r]     = (_Float16)__builtin_exp2f(s1a[r]);
        pa1[4 + r] = (_Float16)__builtin_exp2f(s1b[r]);
      }
      __builtin_amdgcn_s_setprio(1);
      o_acc[0][0] = MFMA_16x16x32(pa0, vfp[0], o_acc[0][0]);
      o_acc[0][1] = MFMA_16x16x32(pa0, vfp[1], o_acc[0][1]);
      o_acc[0][2] = MFMA_16x16x32(pa0, vfp[2], o_acc[0][2]);
      o_acc[0][3] = MFMA_16x16x32(pa0, vfp[3], o_acc[0][3]);
      o_acc[1][0] = MFMA_16x16x32(pa1, vfp[0], o_acc[1][0]);
      o_acc[1][1] = MFMA_16x16x32(pa1, vfp[1], o_acc[1][1]);
      o_acc[1][2] = MFMA_16x16x32(pa1, vfp[2], o_acc[1][2]);
      o_acc[1][3] = MFMA_16x16x32(pa1, vfp[3], o_acc[1][3]);
      l_acc[0] = MFMA_16x16x32(pa0, ones8, l_acc[0]);
      l_acc[1] = MFMA_16x16x32(pa1, ones8, l_acc[1]);
      __builtin_amdgcn_s_setprio(0);
    }

    if (it + 1 < 16) {
#pragma unroll
      for (int i = 0; i < 4; ++i)
        *(f16x8*)&Ks[cur ^ 1][(srow + 32 * i) * 72 + skc] = kreg[i];
#pragma unroll
      for (int i = 0; i < 4; ++i)
        *(f16x8*)&Vs[cur ^ 1][(vrow + 16 * i) * 136 + vcol] = vreg[i];
    }
  }

  const int h = bh & 15;
#pragma unroll
  for (int t = 0; t < 2; ++t) {
    f32x4 linv;
#pragma unroll
    for (int r = 0; r < 4; ++r) linv[r] = 1.0f / l_acc[t][r];
    int qbase = q0 + wave * 32 + t * 16 + quad * 4;
#pragma unroll
    for (int c = 0; c < 4; ++c) {
#pragma unroll
      for (int r = 0; r < 4; ++r) {
        ctx[((size_t)(b * kS + qbase + r)) * kDim + h * kD + c * 16 + l15] =
            (_Float16)(o_acc[t][c][r] * linv[r]);
      }
    }
  }
}

// ------------- output GEMM (measured-best: BM=64, BK=64 reg-staged dbuf, lgkm barriers) -------------
__global__ __launch_bounds__(256, 2) void gemm_out(
    const _Float16* __restrict__ A, const _Float16* __restrict__ Bt,
    const float* __restrict__ bias, float* __restrict__ out) {
  __shared__ alignas(16) _Float16 As[2][64 * 72];
  __shared__ alignas(16) _Float16 Bs[2][128 * 72];
  const int tid = threadIdx.x;
  const int lane = tid & 63;
  const int wave = tid >> 6;
  const int wm = wave & 1, wn = wave >> 1;   // 2x2 waves: 32M x 64N each
  const int l15 = lane & 15, quad = lane >> 4;
  const int m0 = blockIdx.x * 64, n0 = blockIdx.y * 128;

  const int srow = tid >> 3;
  const int skc = (tid & 7) * 8;

  f32x4 acc[2][4] = {};
  f16x8 ra[2], rb[4];

#pragma unroll
  for (int i = 0; i < 2; ++i)
    ra[i] = *(const f16x8*)&A[(size_t)(m0 + srow + 32 * i) * kDim + skc];
#pragma unroll
  for (int i = 0; i < 4; ++i)
    rb[i] = *(const f16x8*)&Bt[(size_t)(n0 + srow + 32 * i) * kDim + skc];
#pragma unroll
  for (int i = 0; i < 2; ++i)
    *(f16x8*)&As[0][(srow + 32 * i) * 72 + skc] = ra[i];
#pragma unroll
  for (int i = 0; i < 4; ++i)
    *(f16x8*)&Bs[0][(srow + 32 * i) * 72 + skc] = rb[i];

  for (int kt = 0; kt < 16; ++kt) {
    const int cur = kt & 1;
    if (kt + 1 < 16) {
      int k0 = (kt + 1) * 64;
#pragma unroll
      for (int i = 0; i < 2; ++i)
        ra[i] = *(const f16x8*)&A[(size_t)(m0 + srow + 32 * i) * kDim + k0 + skc];
#pragma unroll
      for (int i = 0; i < 4; ++i)
        rb[i] = *(const f16x8*)&Bt[(size_t)(n0 + srow + 32 * i) * kDim + k0 + skc];
    }
    wg_barrier_lds();
#pragma unroll
    for (int kk = 0; kk < 2; ++kk) {
      f16x8 af[2], bf[4];
#pragma unroll
      for (int t = 0; t < 2; ++t) af[t] = *(const f16x8*)&As[cur][(wm * 32 + t * 16 + l15) * 72 + kk * 32 + quad * 8];
#pragma unroll
      for (int t = 0; t < 4; ++t) bf[t] = *(const f16x8*)&Bs[cur][(wn * 64 + t * 16 + l15) * 72 + kk * 32 + quad * 8];
      __builtin_amdgcn_s_setprio(1);
#pragma unroll
      for (int i = 0; i < 2; ++i)
#pragma unroll
        for (int j = 0; j < 4; ++j)
          acc[i][j] = MFMA_16x16x32(af[i], bf[j], acc[i][j]);
      __builtin_amdgcn_s_setprio(0);
    }
    if (kt + 1 < 16) {
#pragma unroll
      for (int i = 0; i < 2; ++i)
        *(f16x8*)&As[cur ^ 1][(srow + 32 * i) * 72 + skc] = ra[i];
#pragma unroll
      for (int i = 0; i < 4; ++i)
        *(f16x8*)&Bs[cur ^ 1][(srow + 32 * i) * 72 + skc] = rb[i];
    }
  }

  const int mbase = m0 + wm * 32 + quad * 4;
  const int nbase = n0 + wn * 64 + l15;
#pragma unroll
  for (int j = 0; j < 4; ++j) {
    int n = nbase + j * 16;
    float bv = bias[n];
#pragma unroll
    for (int i = 0; i < 2; ++i) {
      int mrow = mbase + i * 16;
#pragma unroll
      for (int r = 0; r < 4; ++r)
        out[(size_t)(mrow + r) * kDim + n] = acc[i][j][r] + bv;
    }
  }
}

extern "C" void kernel_launch(void* const* d_in, const int* in_sizes, int n_in,
                              void* d_out, int out_size, void* d_ws, size_t ws_size,
                              hipStream_t stream) {
  (void)in_sizes; (void)n_in; (void)out_size; (void)ws_size;
  const float* X    = (const float*)d_in[0];
  const float* mask = (const float*)d_in[1];
  const float* Wq   = (const float*)d_in[2];
  const float* bq   = (const float*)d_in[3];
  const float* Wk   = (const float*)d_in[4];
  const float* bk   = (const float*)d_in[5];
  const float* Wv   = (const float*)d_in[6];
  const float* bv   = (const float*)d_in[7];
  const float* Wo   = (const float*)d_in[8];
  const float* bo   = (const float*)d_in[9];
  float* out = (float*)d_out;

  char* ws = (char*)d_ws;
  _Float16* Xh   = (_Float16*)(ws);                        // 8 MB
  _Float16* Wqt  = (_Float16*)(ws + ((size_t)8  << 20));   // 2 MB each
  _Float16* Wkt  = (_Float16*)(ws + ((size_t)10 << 20));
  _Float16* Wvt  = (_Float16*)(ws + ((size_t)12 << 20));
  _Float16* Wot  = (_Float16*)(ws + ((size_t)14 << 20));
  _Float16* Qh   = (_Float16*)(ws + ((size_t)16 << 20));   // 8 MB each
  _Float16* Kh   = (_Float16*)(ws + ((size_t)24 << 20));
  _Float16* Vh   = (_Float16*)(ws + ((size_t)32 << 20));   // [B][H][D][S]
  _Float16* Ch   = (_Float16*)(ws + ((size_t)40 << 20));   // 8 MB

  cvt_f32_to_f16<<<dim3(kM * kDim / 8 / 256), dim3(256), 0, stream>>>(X, Xh, kM * kDim / 8);
  transpose_cvt_w<<<dim3(16, 16, 4), dim3(256), 0, stream>>>(Wq, Wk, Wv, Wo, Wqt, Wkt, Wvt, Wot);
  gemm_qkv<<<dim3(32, 8, 3), dim3(256), 0, stream>>>(Xh, Wqt, Wkt, Wvt, bq, bk, bv, Qh, Kh, Vh);
  attn<<<dim3(512), dim3(256), 0, stream>>>(Qh, Kh, Vh, mask, Ch);
  gemm_out<<<dim3(64, 8), dim3(256), 0, stream>>>(Ch, Wot, bo, out);
}